// Round 2
// baseline (226.057 us; speedup 1.0000x reference)
//
#include <hip/hip_runtime.h>

typedef __bf16 bf16;
typedef __bf16 bf16x8 __attribute__((ext_vector_type(8)));
typedef float f32x4 __attribute__((ext_vector_type(4)));

__device__ __forceinline__ f32x4 mfma16(bf16x8 a, bf16x8 b, f32x4 c) {
  return __builtin_amdgcn_mfma_f32_16x16x32_bf16(a, b, c, 0, 0, 0);
}

// ---------------- gating: g = softmax(x@gw+gb); xgb[b][i*8+l] = bf16(x[b,i]*g[b,l]);
// also writes g (f32) for the bias epilogue ----------------
__global__ __launch_bounds__(256) void gating_kernel(
    const float* __restrict__ x, const float* __restrict__ gw,
    const float* __restrict__ gb, bf16* __restrict__ xgb,
    float* __restrict__ gbuf) {
  const int b = blockIdx.x, tid = threadIdx.x;
  __shared__ float xs[256];
  __shared__ float gs[8];
  xs[tid] = x[b * 256 + tid];
  __syncthreads();
  if (tid < 8) {
    float acc = gb[tid];
    for (int i = 0; i < 256; ++i) acc += xs[i] * gw[i * 8 + tid];
    gs[tid] = acc;
  }
  __syncthreads();
  if (tid == 0) {
    float m = gs[0];
    for (int l = 1; l < 8; ++l) m = fmaxf(m, gs[l]);
    float s = 0.f, e[8];
    for (int l = 0; l < 8; ++l) { e[l] = expf(gs[l] - m); s += e[l]; }
    float inv = 1.f / s;
    for (int l = 0; l < 8; ++l) gs[l] = e[l] * inv;
  }
  __syncthreads();
  if (tid < 8) gbuf[b * 8 + tid] = gs[tid];
  bf16* dst = xgb + (size_t)b * 2048;
  for (int k = tid; k < 2048; k += 256)
    dst[k] = (bf16)(xs[k >> 3] * gs[k & 7]);
}

// ---------------- weight transform: w (CIN,COUT,4,4) -> wp[p][ocp][t*CIN+ic] bf16 --------
template <int CIN, int COUT, int COUTP>
__global__ __launch_bounds__(256) void convert_w_kernel(
    const float* __restrict__ w, bf16* __restrict__ wp) {
  constexpr int K = 4 * CIN;
  constexpr int total = 4 * COUTP * K;
  int idx = blockIdx.x * 256 + threadIdx.x;
  if (idx >= total) return;
  int ic = idx & (CIN - 1);
  int t = (idx / CIN) & 3;
  int oc = (idx / K) % COUTP;
  int p = idx / (K * COUTP);
  bf16 v = (bf16)0.f;
  if (oc < COUT) {
    int py = p >> 1, px = p & 1, tyi = t >> 1, txi = t & 1;
    int ky = py == 0 ? (tyi ? 3 : 1) : (tyi ? 2 : 0);
    int kx = px == 0 ? (txi ? 3 : 1) : (txi ? 2 : 0);
    v = (bf16)w[((ic * COUT + oc) * 4 + ky) * 4 + kx];
  }
  wp[idx] = v;
}

// ---------------- zero the 1-px halo of a padded channels-last buffer ----------------
template <int HP, int WP, int C>
__global__ __launch_bounds__(256) void border_zero_kernel(bf16* __restrict__ buf) {
  constexpr int NCELL = 2 * WP + 2 * (HP - 2);
  constexpr int C8 = C / 8;
  int idx = blockIdx.x * 256 + threadIdx.x;
  if (idx >= 256 * NCELL * C8) return;
  int c8 = idx % C8;
  int rem = idx / C8;
  int cell = rem % NCELL;
  int b = rem / NCELL;
  int y, x;
  if (cell < WP) { y = 0; x = cell; }
  else if (cell < 2 * WP) { y = HP - 1; x = cell - WP; }
  else { int r2 = cell - 2 * WP; y = 1 + (r2 >> 1); x = (r2 & 1) ? WP - 1 : 0; }
  bf16x8 z = {};
  *(bf16x8*)(buf + ((size_t)(b * HP + y) * WP + x) * C + c8 * 8) = z;
}

// ---------------- ME GEMM: C[b,o] = XG[b,:2048] . bf16(pw[o,:]) + dot(g[b],pb[o])
// block = 512 thr = 8 waves: quadrant q=wv&3 (2x2 of 32x32), K-half kh=wv>>2.
// kh=1 waves accumulate K[1024:2048] and reduce into kh=0 via LDS. B read as f32 direct.
__global__ __launch_bounds__(512, 4) void me_gemm_kernel(
    const bf16* __restrict__ xgb, const float* __restrict__ pw,
    const float* __restrict__ pb, const float* __restrict__ gbuf,
    bf16* __restrict__ h0t) {
  __shared__ float red[4][32 * 33];
  const int tid = threadIdx.x, wv = tid >> 6, l = tid & 63;
  const int lr = l & 15, lkg = l >> 4;
  const int q = wv & 3, kh = wv >> 2;
  const int b0 = blockIdx.y * 64 + (q >> 1) * 32;
  const int o0 = blockIdx.x * 64 + (q & 1) * 32;
  const int k0 = kh * 1024 + lkg * 8;
  const bf16* arow0 = xgb + (size_t)(b0 + lr) * 2048 + k0;
  const bf16* arow1 = arow0 + 16 * 2048;
  const float* brow0 = pw + (size_t)(o0 + lr) * 2048 + k0;
  const float* brow1 = brow0 + 16 * 2048;
  f32x4 acc[2][2] = {};
#pragma unroll 2
  for (int kk = 0; kk < 1024; kk += 32) {
    bf16x8 a0 = *(const bf16x8*)(arow0 + kk);
    bf16x8 a1 = *(const bf16x8*)(arow1 + kk);
    float4 b0l = *(const float4*)(brow0 + kk);
    float4 b0h = *(const float4*)(brow0 + kk + 4);
    float4 b1l = *(const float4*)(brow1 + kk);
    float4 b1h = *(const float4*)(brow1 + kk + 4);
    bf16x8 q0, q1;
    q0[0] = (bf16)b0l.x; q0[1] = (bf16)b0l.y; q0[2] = (bf16)b0l.z; q0[3] = (bf16)b0l.w;
    q0[4] = (bf16)b0h.x; q0[5] = (bf16)b0h.y; q0[6] = (bf16)b0h.z; q0[7] = (bf16)b0h.w;
    q1[0] = (bf16)b1l.x; q1[1] = (bf16)b1l.y; q1[2] = (bf16)b1l.z; q1[3] = (bf16)b1l.w;
    q1[4] = (bf16)b1h.x; q1[5] = (bf16)b1h.y; q1[6] = (bf16)b1h.z; q1[7] = (bf16)b1h.w;
    acc[0][0] = mfma16(a0, q0, acc[0][0]);
    acc[0][1] = mfma16(a0, q1, acc[0][1]);
    acc[1][0] = mfma16(a1, q0, acc[1][0]);
    acc[1][1] = mfma16(a1, q1, acc[1][1]);
  }
  if (kh == 1) {
    float* R = red[q];
#pragma unroll
    for (int m = 0; m < 2; ++m)
#pragma unroll
      for (int n = 0; n < 2; ++n)
#pragma unroll
        for (int r = 0; r < 4; ++r)
          R[(m * 16 + lkg * 4 + r) * 33 + n * 16 + lr] = acc[m][n][r];
  }
  __syncthreads();
  if (kh == 0) {
    const float* R = red[q];
#pragma unroll
    for (int n = 0; n < 2; ++n) {
      int o = o0 + n * 16 + lr;
      float4 p0 = *(const float4*)(pb + o * 8);
      float4 p1 = *(const float4*)(pb + o * 8 + 4);
      int c = o >> 6, y = (o >> 3) & 7, xx = o & 7;
#pragma unroll
      for (int m = 0; m < 2; ++m)
#pragma unroll
        for (int r = 0; r < 4; ++r) {
          int bb = b0 + m * 16 + lkg * 4 + r;
          const float* gr = gbuf + bb * 8;
          float bias = gr[0] * p0.x + gr[1] * p0.y + gr[2] * p0.z + gr[3] * p0.w +
                       gr[4] * p1.x + gr[5] * p1.y + gr[6] * p1.z + gr[7] * p1.w;
          float v = acc[m][n][r] + R[(m * 16 + lkg * 4 + r) * 33 + n * 16 + lr] + bias;
          h0t[((size_t)(bb * 10 + y + 1) * 10 + xx + 1) * 128 + c] = (bf16)v;
        }
    }
  }
}

// ---------------- conv-transpose parity GEMM (unchanged) ----------------
template <int CIN, int HIN, int WIN, int COUTP, int NF, bool RELU, bool F32OUT>
__global__ __launch_bounds__(256) void convt_kernel(
    const bf16* __restrict__ in, const bf16* __restrict__ wp,
    const float* __restrict__ bias, bf16* __restrict__ out,
    float* __restrict__ fout) {
  constexpr int K = 4 * CIN;
  constexpr int HP = HIN + 2, WPD = WIN + 2;
  constexpr int HW = HIN * WIN;
  constexpr int OH = 2 * HIN, OW = 2 * WIN;
  constexpr int OHP = OH + 2, OWP = OW + 2;
  const int p = blockIdx.y, py = p >> 1, px = p & 1;
  const int tid = threadIdx.x, wv = tid >> 6, l = tid & 63;
  const int lr = l & 15, lkg = l >> 4;
  const int row0 = blockIdx.x * 128 + wv * 32;

  int abase[2];
#pragma unroll
  for (int m = 0; m < 2; ++m) {
    int r = row0 + m * 16 + lr;
    int b = r / HW, rem = r % HW;
    int y = rem / WIN, xx = rem % WIN;
    abase[m] = ((b * HP + y + 1) * WPD + xx + 1) * CIN;
  }
  f32x4 acc[2][NF] = {};
#pragma unroll 2
  for (int kk = 0; kk < K; kk += 32) {
    int k = kk + lkg * 8;
    int t = k / CIN, ic = k % CIN;
    int tyi = t >> 1, txi = t & 1;
    int dy = (py == 0) ? (tyi ? -1 : 0) : (tyi ? 0 : 1);
    int dx = (px == 0) ? (txi ? -1 : 0) : (txi ? 0 : 1);
    int aoff = (dy * WPD + dx) * CIN + ic;
    bf16x8 av[2], bv[NF];
#pragma unroll
    for (int m = 0; m < 2; ++m) av[m] = *(const bf16x8*)(in + abase[m] + aoff);
#pragma unroll
    for (int n = 0; n < NF; ++n)
      bv[n] = *(const bf16x8*)(wp + (size_t)(p * COUTP + n * 16 + lr) * K + k);
#pragma unroll
    for (int m = 0; m < 2; ++m)
#pragma unroll
      for (int n = 0; n < NF; ++n) acc[m][n] = mfma16(av[m], bv[n], acc[m][n]);
  }
#pragma unroll
  for (int m = 0; m < 2; ++m)
#pragma unroll
    for (int r4 = 0; r4 < 4; ++r4) {
      int row = row0 + m * 16 + lkg * 4 + r4;
      int b = row / HW, rem = row % HW;
      int y = rem / WIN, xx = rem % WIN;
      int oy = 2 * y + py, ox = 2 * xx + px;
#pragma unroll
      for (int n = 0; n < NF; ++n) {
        int oc = n * 16 + lr;
        float v = acc[m][n][r4];
        if constexpr (F32OUT) {
          if (oc < 3) fout[((size_t)(b * 3 + oc) * OH + oy) * OW + ox] = v + bias[oc];
        } else {
          v += bias[oc];
          if constexpr (RELU) v = fmaxf(v, 0.f);
          out[((size_t)(b * OHP + oy + 1) * OWP + ox + 1) * COUTP + oc] = (bf16)v;
        }
      }
    }
}

// ---------------- launch ----------------
extern "C" void kernel_launch(void* const* d_in, const int* in_sizes, int n_in,
                              void* d_out, int out_size, void* d_ws, size_t ws_size,
                              hipStream_t stream) {
  const float* x  = (const float*)d_in[0];
  const float* gw = (const float*)d_in[1];
  const float* gb = (const float*)d_in[2];
  const float* pw = (const float*)d_in[3];
  const float* pb = (const float*)d_in[4];
  const float* w1 = (const float*)d_in[5];
  const float* b1 = (const float*)d_in[6];
  const float* w2 = (const float*)d_in[7];
  const float* b2 = (const float*)d_in[8];
  const float* w3 = (const float*)d_in[9];
  const float* b3 = (const float*)d_in[10];
  float* outp = (float*)d_out;

  char* ws = (char*)d_ws;
  bf16*  xgb  = (bf16*)(ws + 0);          // 256*2048*2      = 1,048,576
  float* gbuf = (float*)(ws + 1048576);   // 256*8*4         = 8,192
  bf16*  h0t  = (bf16*)(ws + 1056768);    // 256*10*10*128*2 = 6,553,600
  bf16*  w1p  = (bf16*)(ws + 7610368);    // 4*64*512*2      = 262,144
  bf16*  h1   = (bf16*)(ws + 7872512);    // 256*18*18*64*2  = 10,616,832
  bf16*  w2p  = (bf16*)(ws + 18489344);   // 4*32*256*2      = 65,536
  bf16*  h2   = (bf16*)(ws + 18554880);   // 256*34*34*32*2  = 18,939,904
  bf16*  w3p  = (bf16*)(ws + 37494784);   // 4*16*128*2      = 16,384

  // zero only the 1-px halos (interiors are fully overwritten every call)
  border_zero_kernel<10, 10, 128><<<576, 256, 0, stream>>>(h0t);
  border_zero_kernel<18, 18, 64><<<544, 256, 0, stream>>>(h1);
  border_zero_kernel<34, 34, 32><<<528, 256, 0, stream>>>(h2);

  gating_kernel<<<256, 256, 0, stream>>>(x, gw, gb, xgb, gbuf);
  convert_w_kernel<128, 64, 64><<<512, 256, 0, stream>>>(w1, w1p);
  convert_w_kernel<64, 32, 32><<<128, 256, 0, stream>>>(w2, w2p);
  convert_w_kernel<32, 3, 16><<<32, 256, 0, stream>>>(w3, w3p);

  me_gemm_kernel<<<dim3(128, 4), 512, 0, stream>>>(xgb, pw, pb, gbuf, h0t);

  convt_kernel<128, 8, 8, 64, 4, true, false>
      <<<dim3(128, 4), 256, 0, stream>>>(h0t, w1p, b1, h1, nullptr);
  convt_kernel<64, 16, 16, 32, 2, true, false>
      <<<dim3(512, 4), 256, 0, stream>>>(h1, w2p, b2, h2, nullptr);
  convt_kernel<32, 32, 32, 16, 1, false, true>
      <<<dim3(2048, 4), 256, 0, stream>>>(h2, w3p, b3, nullptr, outp);
}

// Round 3
// 122.041 us; speedup vs baseline: 1.8523x; 1.8523x over previous
//
#include <hip/hip_runtime.h>

typedef __bf16 bf16;
typedef __bf16 bf16x8 __attribute__((ext_vector_type(8)));
typedef float f32x4 __attribute__((ext_vector_type(4)));

__device__ __forceinline__ f32x4 mfma16(bf16x8 a, bf16x8 b, f32x4 c) {
  return __builtin_amdgcn_mfma_f32_16x16x32_bf16(a, b, c, 0, 0, 0);
}

// async global->LDS 16B; LDS dest is wave-uniform base, lane l writes base+l*16.
// AS3 via uint truncation (CK idiom: flat shared ptr low 32 bits == LDS offset).
__device__ __forceinline__ void gload16(const void* g, void* l) {
  __builtin_amdgcn_global_load_lds(
      (const __attribute__((address_space(1))) void*)g,
      (__attribute__((address_space(3))) void*)(uint32_t)(size_t)l, 16, 0, 0);
}

// ---------------- gating: g = softmax(x@gw+gb); xgb[b][i*8+l] = bf16(x[b,i]*g[b,l]);
// gbuf = g (f32) for the bias epilogue ----------------
__global__ __launch_bounds__(256) void gating_kernel(
    const float* __restrict__ x, const float* __restrict__ gw,
    const float* __restrict__ gb, bf16* __restrict__ xgb,
    float* __restrict__ gbuf) {
  const int b = blockIdx.x, tid = threadIdx.x;
  __shared__ float xs[256];
  __shared__ float gs[8];
  xs[tid] = x[b * 256 + tid];
  __syncthreads();
  if (tid < 8) {
    float acc = gb[tid];
    for (int i = 0; i < 256; ++i) acc += xs[i] * gw[i * 8 + tid];
    gs[tid] = acc;
  }
  __syncthreads();
  if (tid == 0) {
    float m = gs[0];
    for (int l = 1; l < 8; ++l) m = fmaxf(m, gs[l]);
    float s = 0.f, e[8];
    for (int l = 0; l < 8; ++l) { e[l] = expf(gs[l] - m); s += e[l]; }
    float inv = 1.f / s;
    for (int l = 0; l < 8; ++l) gs[l] = e[l] * inv;
  }
  __syncthreads();
  if (tid < 8) gbuf[b * 8 + tid] = gs[tid];
  bf16* dst = xgb + (size_t)b * 2048;
  for (int k = tid; k < 2048; k += 256)
    dst[k] = (bf16)(xs[k >> 3] * gs[k & 7]);
}

// ---------------- pw f32 -> pwb bf16 (plain layout) ----------------
__global__ __launch_bounds__(256) void convert_pw_kernel(
    const float* __restrict__ pw, bf16* __restrict__ pwb) {
  const size_t base = (size_t)blockIdx.x * 2048 + threadIdx.x * 8;
  float4 v0 = *(const float4*)(pw + base);
  float4 v1 = *(const float4*)(pw + base + 4);
  bf16x8 r;
  r[0] = (bf16)v0.x; r[1] = (bf16)v0.y; r[2] = (bf16)v0.z; r[3] = (bf16)v0.w;
  r[4] = (bf16)v1.x; r[5] = (bf16)v1.y; r[6] = (bf16)v1.z; r[7] = (bf16)v1.w;
  *(bf16x8*)(pwb + base) = r;
}

// ---------------- weight transform: w (CIN,COUT,4,4) -> wp[p][ocp][t*CIN+ic] bf16 --------
template <int CIN, int COUT, int COUTP>
__global__ __launch_bounds__(256) void convert_w_kernel(
    const float* __restrict__ w, bf16* __restrict__ wp) {
  constexpr int K = 4 * CIN;
  constexpr int total = 4 * COUTP * K;
  int idx = blockIdx.x * 256 + threadIdx.x;
  if (idx >= total) return;
  int ic = idx & (CIN - 1);
  int t = (idx / CIN) & 3;
  int oc = (idx / K) % COUTP;
  int p = idx / (K * COUTP);
  bf16 v = (bf16)0.f;
  if (oc < COUT) {
    int py = p >> 1, px = p & 1, tyi = t >> 1, txi = t & 1;
    int ky = py == 0 ? (tyi ? 3 : 1) : (tyi ? 2 : 0);
    int kx = px == 0 ? (txi ? 3 : 1) : (txi ? 2 : 0);
    v = (bf16)w[((ic * COUT + oc) * 4 + ky) * 4 + kx];
  }
  wp[idx] = v;
}

// ---------------- zero the 1-px halo of a padded channels-last buffer ----------------
template <int HP, int WP, int C>
__global__ __launch_bounds__(256) void border_zero_kernel(bf16* __restrict__ buf) {
  constexpr int NCELL = 2 * WP + 2 * (HP - 2);
  constexpr int C8 = C / 8;
  int idx = blockIdx.x * 256 + threadIdx.x;
  if (idx >= 256 * NCELL * C8) return;
  int c8 = idx % C8;
  int rem = idx / C8;
  int cell = rem % NCELL;
  int b = rem / NCELL;
  int y, x;
  if (cell < WP) { y = 0; x = cell; }
  else if (cell < 2 * WP) { y = HP - 1; x = cell - WP; }
  else { int r2 = cell - 2 * WP; y = 1 + (r2 >> 1); x = (r2 & 1) ? WP - 1 : 0; }
  bf16x8 z = {};
  *(bf16x8*)(buf + ((size_t)(b * HP + y) * WP + x) * C + c8 * 8) = z;
}

// ---------------- ME GEMM: C[o,b] = pwb[o,:] . xgb[b,:] (+ g.pb bias) -> h0t ----------
// M=o (8192), N=b (256), K=2048. 64x64 tile, BK=64, LDS double-buffer via global_load_lds
// with pre-swizzled source (XOR byte ^ ((row&7)<<4)); 4 waves 2x2, wave tile 32x32.
__global__ __launch_bounds__(256) void me_gemm_kernel(
    const bf16* __restrict__ pwb, const bf16* __restrict__ xgb,
    const float* __restrict__ pb, const float* __restrict__ gbuf,
    bf16* __restrict__ h0t) {
  __shared__ char sAB[32768];  // buf0: A@0,B@8192 ; buf1: A@16384,B@24576
  const int tid = threadIdx.x, wv = tid >> 6, l = tid & 63;
  const int lr = l & 15, lkg = l >> 4;
  const int wm = wv >> 1, wn = wv & 1;
  const int oM0 = blockIdx.x * 64, bN0 = blockIdx.y * 64;

  // staging source pointers (chunk t=tid and t+256)
  const int r1 = tid >> 3, cc1 = tid & 7;
  const int sb1 = (cc1 * 16) ^ ((r1 & 7) << 4);
  const int r2 = r1 + 32;
  const int sb2 = (cc1 * 16) ^ ((r2 & 7) << 4);
  const bf16* pA1 = pwb + (size_t)(oM0 + r1) * 2048 + (sb1 >> 1);
  const bf16* pA2 = pwb + (size_t)(oM0 + r2) * 2048 + (sb2 >> 1);
  const bf16* pB1 = xgb + (size_t)(bN0 + r1) * 2048 + (sb1 >> 1);
  const bf16* pB2 = xgb + (size_t)(bN0 + r2) * 2048 + (sb2 >> 1);
  char* lb0 = sAB + wv * 1024;

  // prologue: stage kt=0 into buf0
  gload16(pA1, lb0);
  gload16(pA2, lb0 + 4096);
  gload16(pB1, lb0 + 8192);
  gload16(pB2, lb0 + 12288);

  // hoisted swizzled read offsets
  int raddrA[2][2], raddrB[2][2];
#pragma unroll
  for (int m = 0; m < 2; ++m) {
    int ra = wm * 32 + m * 16 + lr;
#pragma unroll
    for (int ks = 0; ks < 2; ++ks)
      raddrA[m][ks] = ra * 128 + ((ks * 64 + lkg * 16) ^ ((ra & 7) << 4));
  }
#pragma unroll
  for (int n = 0; n < 2; ++n) {
    int rb = wn * 32 + n * 16 + lr;
#pragma unroll
    for (int ks = 0; ks < 2; ++ks)
      raddrB[n][ks] = 8192 + rb * 128 + ((ks * 64 + lkg * 16) ^ ((rb & 7) << 4));
  }

  f32x4 acc[2][2] = {};
  __syncthreads();
#pragma unroll 2
  for (int kt = 0; kt < 32; ++kt) {
    const int cur = (kt & 1) * 16384;
    if (kt < 31) {
      char* lb = sAB + (((kt + 1) & 1) * 16384) + wv * 1024;
      const int ke = (kt + 1) * 64;
      gload16(pA1 + ke, lb);
      gload16(pA2 + ke, lb + 4096);
      gload16(pB1 + ke, lb + 8192);
      gload16(pB2 + ke, lb + 12288);
    }
    bf16x8 af[2][2], bfr[2][2];
#pragma unroll
    for (int ks = 0; ks < 2; ++ks) {
#pragma unroll
      for (int m = 0; m < 2; ++m)
        af[m][ks] = *(const bf16x8*)(sAB + cur + raddrA[m][ks]);
#pragma unroll
      for (int n = 0; n < 2; ++n)
        bfr[n][ks] = *(const bf16x8*)(sAB + cur + raddrB[n][ks]);
    }
#pragma unroll
    for (int ks = 0; ks < 2; ++ks)
#pragma unroll
      for (int m = 0; m < 2; ++m)
#pragma unroll
        for (int n = 0; n < 2; ++n)
          acc[m][n] = mfma16(af[m][ks], bfr[n][ks], acc[m][n]);
    __syncthreads();
  }

  // epilogue: + dot(g[b], pb[o]), write h0t padded channels-last
  float4 g0[2], g1[2];
#pragma unroll
  for (int n = 0; n < 2; ++n) {
    int b = bN0 + wn * 32 + n * 16 + lr;
    g0[n] = *(const float4*)(gbuf + b * 8);
    g1[n] = *(const float4*)(gbuf + b * 8 + 4);
  }
#pragma unroll
  for (int m = 0; m < 2; ++m)
#pragma unroll
    for (int r = 0; r < 4; ++r) {
      int o = oM0 + wm * 32 + m * 16 + lkg * 4 + r;
      float4 p0 = *(const float4*)(pb + o * 8);
      float4 p1 = *(const float4*)(pb + o * 8 + 4);
      int c = o >> 6, y = (o >> 3) & 7, xx = o & 7;
#pragma unroll
      for (int n = 0; n < 2; ++n) {
        int b = bN0 + wn * 32 + n * 16 + lr;
        float bias = g0[n].x * p0.x + g0[n].y * p0.y + g0[n].z * p0.z + g0[n].w * p0.w +
                     g1[n].x * p1.x + g1[n].y * p1.y + g1[n].z * p1.z + g1[n].w * p1.w;
        h0t[((size_t)(b * 10 + y + 1) * 10 + xx + 1) * 128 + c] = (bf16)(acc[m][n][r] + bias);
      }
    }
}

// ---------------- conv-transpose: LDS-staged input patch (+ weights for conv2/3) -------
// Block = one parity x YB output rows of one image. Input patch (YB+2)x(W+2)xCIN staged
// via gload16 with XOR-swizzled source; K-loop is pure LDS (conv1 weights from L2).
template <int CIN, int H, int YB, int COUTP, int WM, int NF, int SWM,
          bool WLDS, int INIT, int WIT, bool RELU, bool F32OUT, int SIN_SZ, int SW_SZ>
__global__ __launch_bounds__(256) void convt_kernel(
    const bf16* __restrict__ in, const bf16* __restrict__ wp,
    const float* __restrict__ bias, bf16* __restrict__ out,
    float* __restrict__ fout) {
  constexpr int W = H, WROW = W + 2, ROWB = CIN * 2, GRS = ROWB / 16;
  constexpr int LGR = (GRS == 16) ? 4 : (GRS == 8) ? 3 : 2;
  constexpr int LW = (W == 8) ? 3 : (W == 16) ? 4 : 5;
  constexpr int K = 4 * CIN;
  constexpr int CHUNKS = (YB + 2) * WROW * GRS;
  constexpr int WGR = K / 8;  // 16B granules per weight row
  __shared__ char sIn[SIN_SZ];
  __shared__ char sW[SW_SZ];

  const int tid = threadIdx.x, wv = tid >> 6, l = tid & 63;
  const int nyb = H / YB;
  const int img = blockIdx.x / nyb, y0 = (blockIdx.x % nyb) * YB;
  const int p = blockIdx.y, py = p >> 1, px = p & 1;

  // ---- stage input patch ----
#pragma unroll
  for (int it = 0; it < INIT; ++it) {
    int t = it * 256 + tid;
    int tc = t < CHUNKS ? t : CHUNKS - 1;
    int pix = tc >> LGR, cc = tc & (GRS - 1);
    int ly = pix / WROW, lx = pix % WROW;
    int sb = (cc * 16) ^ ((pix & SWM) << 4);
    gload16(in + ((size_t)((img * (H + 2) + y0 + ly) * (W + 2) + lx)) * CIN + (sb >> 1),
            sIn + it * 4096 + wv * 1024);
  }
  // ---- stage weights (conv2/3) ----
  if constexpr (WLDS) {
#pragma unroll
    for (int it = 0; it < WIT; ++it) {
      int t = it * 256 + tid;
      int oc = t / WGR, cc = t % WGR;
      int sb = (cc * 16) ^ ((oc & 7) << 4);
      gload16(wp + (size_t)(p * COUTP + oc) * K + (sb >> 1), sW + it * 4096 + wv * 1024);
    }
  }
  __syncthreads();

  const int lr = l & 15, lkg = l >> 4;
  const int wm = wv & (WM - 1), wn = wv / WM;
  int pcen[2];
#pragma unroll
  for (int m = 0; m < 2; ++m) {
    int r = wm * 32 + m * 16 + lr;
    pcen[m] = ((r >> LW) + 1) * WROW + (r & (W - 1)) + 1;
  }

  f32x4 acc[2][NF] = {};
#pragma unroll 4
  for (int kk = 0; kk < K; kk += 32) {
    const int t4 = kk / CIN;
    const int tyi = t4 >> 1, txi = t4 & 1;
    const int dy = (py == 0) ? (tyi ? -1 : 0) : (tyi ? 0 : 1);
    const int dx = (px == 0) ? (txi ? -1 : 0) : (txi ? 0 : 1);
    const int icb = (kk % CIN) * 2 + lkg * 16;
    bf16x8 av[2], bv[NF];
#pragma unroll
    for (int m = 0; m < 2; ++m) {
      int pixd = pcen[m] + dy * WROW + dx;
      av[m] = *(const bf16x8*)(sIn + pixd * ROWB + (icb ^ ((pixd & SWM) << 4)));
    }
#pragma unroll
    for (int n = 0; n < NF; ++n) {
      int oc = (wn * NF + n) * 16 + lr;
      if constexpr (WLDS) {
        int kb = kk * 2 + lkg * 16;
        bv[n] = *(const bf16x8*)(sW + oc * (K * 2) + (kb ^ ((oc & 7) << 4)));
      } else {
        bv[n] = *(const bf16x8*)(wp + (size_t)(p * COUTP + oc) * K + kk + lkg * 8);
      }
    }
#pragma unroll
    for (int m = 0; m < 2; ++m)
#pragma unroll
      for (int n = 0; n < NF; ++n) acc[m][n] = mfma16(av[m], bv[n], acc[m][n]);
  }

#pragma unroll
  for (int m = 0; m < 2; ++m)
#pragma unroll
    for (int r4 = 0; r4 < 4; ++r4) {
      int r = wm * 32 + m * 16 + lkg * 4 + r4;
      int yy = r >> LW, xx = r & (W - 1);
      int oy = 2 * (y0 + yy) + py, ox = 2 * xx + px;
#pragma unroll
      for (int n = 0; n < NF; ++n) {
        int oc = (wn * NF + n) * 16 + lr;
        float v = acc[m][n][r4];
        if constexpr (F32OUT) {
          if (oc < 3) fout[((size_t)(img * 3 + oc) * (2 * H) + oy) * (2 * H) + ox] = v + bias[oc];
        } else {
          v += bias[oc];
          if constexpr (RELU) v = fmaxf(v, 0.f);
          out[((size_t)(img * (2 * H + 2) + oy + 1) * (2 * H + 2) + ox + 1) * COUTP + oc] = (bf16)v;
        }
      }
    }
}

// ---------------- launch ----------------
extern "C" void kernel_launch(void* const* d_in, const int* in_sizes, int n_in,
                              void* d_out, int out_size, void* d_ws, size_t ws_size,
                              hipStream_t stream) {
  const float* x  = (const float*)d_in[0];
  const float* gw = (const float*)d_in[1];
  const float* gb = (const float*)d_in[2];
  const float* pw = (const float*)d_in[3];
  const float* pb = (const float*)d_in[4];
  const float* w1 = (const float*)d_in[5];
  const float* b1 = (const float*)d_in[6];
  const float* w2 = (const float*)d_in[7];
  const float* b2 = (const float*)d_in[8];
  const float* w3 = (const float*)d_in[9];
  const float* b3 = (const float*)d_in[10];
  float* outp = (float*)d_out;

  char* ws = (char*)d_ws;
  bf16*  xgb  = (bf16*)(ws + 0);          // 1,048,576
  float* gbuf = (float*)(ws + 1048576);   // 8,192
  bf16*  pwb  = (bf16*)(ws + 1056768);    // 33,554,432
  bf16*  h0t  = (bf16*)(ws + 34611200);   // 6,553,600
  bf16*  w1p  = (bf16*)(ws + 41164800);   // 262,144
  bf16*  h1   = (bf16*)(ws + 41426944);   // 10,616,832
  bf16*  w2p  = (bf16*)(ws + 52043776);   // 65,536
  bf16*  h2   = (bf16*)(ws + 52109312);   // 18,939,904
  bf16*  w3p  = (bf16*)(ws + 71049216);   // 16,384

  border_zero_kernel<10, 10, 128><<<576, 256, 0, stream>>>(h0t);
  border_zero_kernel<18, 18, 64><<<544, 256, 0, stream>>>(h1);
  border_zero_kernel<34, 34, 32><<<528, 256, 0, stream>>>(h2);

  gating_kernel<<<256, 256, 0, stream>>>(x, gw, gb, xgb, gbuf);
  convert_pw_kernel<<<8192, 256, 0, stream>>>(pw, pwb);
  convert_w_kernel<128, 64, 64><<<512, 256, 0, stream>>>(w1, w1p);
  convert_w_kernel<64, 32, 32><<<128, 256, 0, stream>>>(w2, w2p);
  convert_w_kernel<32, 3, 16><<<32, 256, 0, stream>>>(w3, w3p);

  me_gemm_kernel<<<dim3(128, 4), 256, 0, stream>>>(pwb, xgb, pb, gbuf, h0t);

  // conv1: CIN=128,H=8,YB=8, COUTP=64, WM=2,NF=2, SWM=7, weights direct (L2)
  convt_kernel<128, 8, 8, 64, 2, 2, 7, false, 7, 0, true, false, 28672, 16>
      <<<dim3(256, 4), 256, 0, stream>>>(h0t, w1p, b1, h1, nullptr);
  // conv2: CIN=64,H=16,YB=8, COUTP=32, WM=4,NF=2, SWM=7, weights in LDS
  convt_kernel<64, 16, 8, 32, 4, 2, 7, true, 6, 4, true, false, 24576, 16384>
      <<<dim3(512, 4), 256, 0, stream>>>(h1, w2p, b2, h2, nullptr);
  // conv3: CIN=32,H=32,YB=4, COUTP=16, WM=4,NF=1, SWM=3, weights in LDS, f32 out
  convt_kernel<32, 32, 4, 16, 4, 1, 3, true, 4, 1, false, true, 16384, 4096>
      <<<dim3(2048, 4), 256, 0, stream>>>(h2, w3p, b3, nullptr, outp);
}